// Round 3
// baseline (1232.893 us; speedup 1.0000x reference)
//
#include <hip/hip_runtime.h>
#include <hip/hip_bf16.h>

#define DIN 49
#define HIN 32
#define WIN 64
#define CIN 32
#define DOUT 193
#define HOUT 256
#define WOUT 512
#define NPIX (HOUT * WOUT)      // 131072
#define NUPS (DOUT * NPIX)      // 25296896
#define NCONV (DIN * HIN * WIN) // 100352
#define DSPLIT 32               // d-planes per LGA block
#define NZ 7                    // ceil(193/32)

// ---------------------------------------------------------------------------
// Kernel 1: 3x3x3 conv, 32 -> 1 channels, zero pad 1, fp32 accumulate.
// ---------------------------------------------------------------------------
__global__ void conv3d_kernel(const float* __restrict__ x,
                              const float* __restrict__ w,
                              float* __restrict__ c) {
    __shared__ float ws[CIN * 27];
    for (int t = threadIdx.x; t < CIN * 27; t += blockDim.x)
        ws[t] = w[t];
    __syncthreads();

    int idx = blockIdx.x * blockDim.x + threadIdx.x;
    if (idx >= NCONV) return;
    int wq = idx % WIN;
    int t2 = idx / WIN;
    int hq = t2 % HIN;
    int dq = t2 / HIN;

    float acc = 0.f;
    for (int ci = 0; ci < CIN; ++ci) {
        const float* xb = x + ci * NCONV;
        const float* wb = ws + ci * 27;
#pragma unroll
        for (int kd = 0; kd < 3; ++kd) {
            int zd = dq + kd - 1;
            if (zd < 0 || zd >= DIN) continue;
#pragma unroll
            for (int kh = 0; kh < 3; ++kh) {
                int zh = hq + kh - 1;
                if (zh < 0 || zh >= HIN) continue;
#pragma unroll
                for (int kw = 0; kw < 3; ++kw) {
                    int zw = wq + kw - 1;
                    if (zw < 0 || zw >= WIN) continue;
                    acc += xb[(zd * HIN + zh) * WIN + zw] *
                           wb[(kd * 3 + kh) * 3 + kw];
                }
            }
        }
    }
    c[idx] = acc;
}

// ---------------------------------------------------------------------------
// Kernel 2: trilinear upsample, 8 outputs/thread along w, uint4 stores.
// c: [49][32][64] fp32 -> u: [193][256][512] bf16
// ---------------------------------------------------------------------------
__global__ void upsample_kernel(const float* __restrict__ c,
                                __hip_bfloat16* __restrict__ u) {
    int t = blockIdx.x * blockDim.x + threadIdx.x;
    int wc = t & 63;            // w-group (8 outputs), input col ~ wc
    int rest = t >> 6;
    int hh = rest & 255;
    int dd = rest >> 8;
    if (dd >= DOUT) return;

    float fd = (dd + 0.5f) * (49.0f / 193.0f) - 0.5f;
    fd = fminf(fmaxf(fd, 0.f), (float)(DIN - 1));
    int d0 = min((int)fd, DIN - 2);
    float ad = fd - (float)d0;

    float fh = (hh + 0.5f) * 0.125f - 0.5f;
    fh = fminf(fmaxf(fh, 0.f), (float)(HIN - 1));
    int h0 = min((int)fh, HIN - 2);
    float ah = fh - (float)h0;

    // 3 columns (wc-1, wc, wc+1 clamped) x 4 rows, fused over d,h up front.
    int cm1 = max(wc - 1, 0);
    int cp1 = min(wc + 1, WIN - 1);
    const float* p00 = c + (d0 * HIN + h0) * WIN;
    const float* p01 = p00 + WIN;           // h0+1 (d0, h0+1 valid: h0<=30)
    const float* p10 = p00 + HIN * WIN;     // d0+1
    const float* p11 = p10 + WIN;

    float a[3];
    {
        float q00, q01, q10, q11;
        q00 = p00[cm1]; q01 = p01[cm1]; q10 = p10[cm1]; q11 = p11[cm1];
        a[0] = (q00 + ah * (q01 - q00)) * (1.f - ad) +
               (q10 + ah * (q11 - q10)) * ad;
        q00 = p00[wc]; q01 = p01[wc]; q10 = p10[wc]; q11 = p11[wc];
        a[1] = (q00 + ah * (q01 - q00)) * (1.f - ad) +
               (q10 + ah * (q11 - q10)) * ad;
        q00 = p00[cp1]; q01 = p01[cp1]; q10 = p10[cp1]; q11 = p11[cp1];
        a[2] = (q00 + ah * (q01 - q00)) * (1.f - ad) +
               (q10 + ah * (q11 - q10)) * ad;
    }

    union {
        unsigned short us[8];
        uint4 v4;
    } pk;
#pragma unroll
    for (int i = 0; i < 8; ++i) {
        float fw = (float)(wc * 8 + i) * 0.125f + (0.0625f - 0.5f);
        fw = fminf(fmaxf(fw, 0.f), (float)(WIN - 1));
        int w0 = min((int)fw, WIN - 2);
        float aw = fw - (float)w0;
        int idx = w0 - (wc - 1); // 0 or 1
        float lo = (idx == 0) ? a[0] : a[1];
        float hi = (idx == 0) ? a[1] : a[2];
        float v = lo + aw * (hi - lo);
        __hip_bfloat16 b = __float2bfloat16(v);
        unsigned short usv;
        __builtin_memcpy(&usv, &b, 2);
        pk.us[i] = usv;
    }
    *((uint4*)(u + (size_t)dd * NPIX + hh * WOUT + wc * 8)) = pk.v4;
}

// ---------------------------------------------------------------------------
// LGA kernel, d-split. Block = 16x16 pixel tile, covers DSPLIT d-planes.
// Writes aggregated volume (bf16). Row stride 24 in LDS => 2-way banks (free).
// ---------------------------------------------------------------------------
__global__ __launch_bounds__(256) void lga_kernel(
    const __hip_bfloat16* __restrict__ xin,
    const float* __restrict__ lg1,
    __hip_bfloat16* __restrict__ yout) {
    const int tx = threadIdx.x & 15;
    const int ty = threadIdx.x >> 4;
    const int w0p = blockIdx.x * 16;
    const int h0p = blockIdx.y * 16;
    const int zb = blockIdx.z * DSPLIT;
    const int pix = (h0p + ty) * WOUT + (w0p + tx);

    // Load + L1-normalize guidance into registers.
    float g[75];
    float asum = 0.f;
#pragma unroll
    for (int ch = 0; ch < 75; ++ch) {
        g[ch] = lg1[ch * NPIX + pix];
        asum += fabsf(g[ch]);
    }
    float inv = 1.0f / fmaxf(asum, 1e-12f);
#pragma unroll
    for (int ch = 0; ch < 75; ++ch) g[ch] *= inv;

    __shared__ float su[10 * 480]; // 10 planes x 20 rows x stride 24, 19.2 KB

    const int dend = min(zb + DSPLIT, DOUT);
    for (int d0 = zb; d0 < dend; d0 += 8) {
        __syncthreads();
        // Stage planes gd = d0-1 .. d0+8 (zeros outside volume/image).
        for (int t = threadIdx.x; t < 4000; t += 256) {
            int dl = t / 400;
            int rc = t - dl * 400;
            int r = rc / 20;
            int cc = rc - r * 20;
            int gd = d0 - 1 + dl;
            int gh = h0p - 2 + r;
            int gw = w0p - 2 + cc;
            float v = 0.f;
            if (gd >= 0 && gd < DOUT && gh >= 0 && gh < HOUT && gw >= 0 &&
                gw < WOUT)
                v = __bfloat162float(xin[gd * NPIX + gh * WOUT + gw]);
            su[dl * 480 + r * 24 + cc] = v;
        }
        __syncthreads();

        float acc[8] = {0.f, 0.f, 0.f, 0.f, 0.f, 0.f, 0.f, 0.f};
#pragma unroll
        for (int i = 0; i < 5; ++i) {
#pragma unroll
            for (int j = 0; j < 5; ++j) {
                const int base = (ty + i) * 24 + (tx + j);
                float v[10];
#pragma unroll
                for (int dl = 0; dl < 10; ++dl) v[dl] = su[dl * 480 + base];
                const float g0 = g[i * 5 + j];
                const float g1 = g[25 + i * 5 + j];
                const float g2 = g[50 + i * 5 + j];
#pragma unroll
                for (int dd = 0; dd < 8; ++dd)
                    acc[dd] += g0 * v[dd + 1] + g1 * v[dd] + g2 * v[dd + 2];
            }
        }

#pragma unroll
        for (int dd = 0; dd < 8; ++dd) {
            int d = d0 + dd;
            if (d < dend) yout[(size_t)d * NPIX + pix] = __float2bfloat16(acc[dd]);
        }
    }
}

// ---------------------------------------------------------------------------
// Kernel 4: online softmin over d + disparity regression. One thread = pixel.
// ---------------------------------------------------------------------------
__global__ void reduce_kernel(const __hip_bfloat16* __restrict__ y,
                              float* __restrict__ out) {
    int pix = blockIdx.x * blockDim.x + threadIdx.x;
    float m = -1e30f, l = 0.f, s = 0.f;
    for (int d = 0; d < 192; d += 4) {
        float v0 = -__bfloat162float(y[(size_t)(d + 0) * NPIX + pix]);
        float v1 = -__bfloat162float(y[(size_t)(d + 1) * NPIX + pix]);
        float v2 = -__bfloat162float(y[(size_t)(d + 2) * NPIX + pix]);
        float v3 = -__bfloat162float(y[(size_t)(d + 3) * NPIX + pix]);
        float mx = fmaxf(fmaxf(fmaxf(v0, v1), fmaxf(v2, v3)), m);
        float sc = __expf(m - mx);
        float e0 = __expf(v0 - mx);
        float e1 = __expf(v1 - mx);
        float e2 = __expf(v2 - mx);
        float e3 = __expf(v3 - mx);
        l = l * sc + e0 + e1 + e2 + e3;
        s = s * sc + e0 * (float)d + e1 * (float)(d + 1) + e2 * (float)(d + 2) +
            e3 * (float)(d + 3);
        m = mx;
    }
    { // d = 192 tail
        float v = -__bfloat162float(y[(size_t)192 * NPIX + pix]);
        float mx = fmaxf(v, m);
        float sc = __expf(m - mx);
        float e = __expf(v - mx);
        l = l * sc + e;
        s = s * sc + e * 192.f;
    }
    out[pix] = s / l;
}

// ---------------------------------------------------------------------------
extern "C" void kernel_launch(void* const* d_in, const int* in_sizes, int n_in,
                              void* d_out, int out_size, void* d_ws,
                              size_t ws_size, hipStream_t stream) {
    const float* x = (const float*)d_in[0];
    const float* lg1 = (const float*)d_in[1];
    const float* cw = (const float*)d_in[2];
    float* out = (float*)d_out;

    // ws layout: c fp32 [100352] | u bf16 [25296896] | y1 bf16 [25296896]
    // LGA2 writes y2 back into u's buffer (u dead after LGA1).
    float* c = (float*)d_ws;
    __hip_bfloat16* u = (__hip_bfloat16*)((char*)d_ws + (size_t)NCONV * 4);
    __hip_bfloat16* y1 = u + (size_t)NUPS;

    conv3d_kernel<<<(NCONV + 255) / 256, 256, 0, stream>>>(x, cw, c);
    upsample_kernel<<<(DOUT * HOUT * 64 + 255) / 256, 256, 0, stream>>>(c, u);

    dim3 grid(WOUT / 16, HOUT / 16, NZ); // 32 x 16 x 7 = 3584 blocks
    lga_kernel<<<grid, 256, 0, stream>>>(u, lg1, y1);
    lga_kernel<<<grid, 256, 0, stream>>>(y1, lg1, u);

    reduce_kernel<<<NPIX / 256, 256, 0, stream>>>(u, out);
}